// Round 11
// baseline (251.266 us; speedup 1.0000x reference)
//
#include <hip/hip_runtime.h>
#include <hip/hip_bf16.h>

#define N_ROWS 8192
#define D_DIM  4096
#define E_DIM  64
#define BR     32                 // rows per block
#define BK     128                // fp32 K elems per staged chunk
#define NCH    (D_DIM / BK)       // 32 chunks
#define NSTEP  (BK / 32)          // 4 K32-steps per chunk

typedef __attribute__((ext_vector_type(8))) short  short8;
typedef __attribute__((ext_vector_type(4))) float  floatx4;
typedef __attribute__((ext_vector_type(8))) float  float8;

// async global->LDS, 16B per lane; LDS dest is wave-uniform base + lane*16
__device__ inline void gload16(const void* g, void* l) {
  __builtin_amdgcn_global_load_lds(
      (const __attribute__((address_space(1))) void*)g,
      (__attribute__((address_space(3))) void*)l, 16, 0, 0);
}

// Split an fp32 vector into hi (RNE bf16) + lo (chopped bf16 of remainder).
// Bitwise-identical math to the verified kernel -> identical numerics.
__device__ inline void cvt_split(const float8& f, short8& hi, short8& lo) {
#pragma unroll
  for (int j = 0; j < 8; ++j) {
    float x = f[j];
    unsigned int u  = __builtin_bit_cast(unsigned int, x);
    unsigned int rh = (u + 0x7FFFu + ((u >> 16) & 1u)) >> 16;  // RNE to bf16
    hi[j] = (short)rh;
    float hf = __builtin_bit_cast(float, rh << 16);
    float lf = x - hf;
    unsigned int ul = __builtin_bit_cast(unsigned int, lf);
    lo[j] = (short)(ul >> 16);                                  // chop
  }
}

// ---------------------------------------------------------------------------
// Prep kernel: convert W fp32 [64][4096] -> d_ws split-bf16 in FRAGMENT order.
// For K32-step s (0..127), expert tile e (0..3), plane p (hi/lo), lane l:
//   16B fragment = W rows e*16+(l&15), k = s*32+(l>>4)*8 .. +7
//   stored at ws + s*8192 + e*2048 + p*1024 + l*16       (total 1 MB)
// ---------------------------------------------------------------------------
__global__ __launch_bounds__(512) void prep_w(const void* __restrict__ xv,
                                              const void* __restrict__ wv,
                                              void* __restrict__ ws) {
  __shared__ int sflag;
  const int tid = threadIdx.x;
  if (tid < 64) {   // dtype probe (skip conversion if inputs are bf16)
    unsigned int v = ((const unsigned int*)xv)[(size_t)tid * 997];
    unsigned int e = (v >> 7) & 0xFFu;
    unsigned long long m = __ballot(e >= 100u && e <= 140u);
    if (tid == 0) sflag = (__popcll(m) > 32) ? 1 : 0;
  }
  __syncthreads();
  if (sflag) return;
  const int t    = blockIdx.x * 512 + tid;   // 64 blocks x 512 = 32768
  const int lane = t & 63;
  const int idx  = t >> 6;                    // s*4 + e
  const int s    = idx >> 2;
  const int e    = idx & 3;
  const int row  = e * 16 + (lane & 15);
  const int col  = s * 32 + (lane >> 4) * 8;
  float8 f = *(const float8*)((const float*)wv + (size_t)row * D_DIM + col);
  short8 h, l;
  cvt_split(f, h, l);
  char* d = (char*)ws + (size_t)idx * 2048 + lane * 16;
  *(short8*)d          = h;
  *(short8*)(d + 1024) = l;
}

// ---------------------------------------------------------------------------
// Main fused router: 256 blocks x 256 threads. Block = 32 rows, all 64
// experts. 4 waves: wave w -> expert tile w, BOTH 16-row subtiles (B reuse:
// each B frag feeds 6 MFMAs; grid-wide B traffic 256 MB).
//
// Round-11 theory: every C-level register prefetch of B got SUNK by the
// compiler across the barrier (r3 VGPR=56, r8=104, r9=64), re-exposing
// ~500-900cy per K-step; asm-volatile loads crash the harness (r10).
// Fix: B is staged through LDS via global_load_lds DMA — the one prefetch
// mechanism PROVEN pinned in this session (r9's x staging). Now ALL K-loop
// memory traffic (x fp32 + B split-bf16 frags) is pinned, double-buffered
// DMA drained by the chunk barrier; the scheduler has nothing to collapse.
//  * x LDS [32 rows][32 quanta], quantum-XOR q^(row&7) via pre-swizzled
//    global source (rule #21); conflict-light ds_read_b128.
//  * B LDS [wave][step][plane][1KB], lane-linear both sides (conflict-free).
//  * cvt_split after ds_read (VALU was idle); numerics bitwise = r7.
//  * LDS 105 KB -> 1 block/CU; grid 256 = 1 block per CU, no tail.
// ---------------------------------------------------------------------------
__global__ __launch_bounds__(256, 1) void router_kernel(
    const void* __restrict__ xv, const void* __restrict__ wv,
    const void* __restrict__ bv, const void* __restrict__ wsv,
    float* __restrict__ out) {
  __shared__ __align__(16) char xs[2][16384];   // [buf][row 32][q 32][16B] fp32
  __shared__ __align__(16) char bs[2][32768];   // [buf][wave][step][plane][1KB]
  __shared__ float lg[BR][E_DIM + 4];
  __shared__ int   sflag;

  const int tid = threadIdx.x;

  if (tid < 64) {   // dtype probe
    unsigned int v = ((const unsigned int*)xv)[(size_t)tid * 997];
    unsigned int e = (v >> 7) & 0xFFu;
    unsigned long long m = __ballot(e >= 100u && e <= 140u);
    if (tid == 0) sflag = (__popcll(m) > 32) ? 1 : 0;
  }
  __syncthreads();
  const int isbf = sflag;

  const int wave = tid >> 6;            // expert tile 0..3
  const int lane = tid & 63;
  const int lm   = lane & 15;           // A: row-in-subtile  B: expert-in-tile
  const int t4   = lane >> 4;           // k sub-slot within 32-wide K step
  const int r0   = blockIdx.x * BR;

  floatx4 acc0 = {0.f, 0.f, 0.f, 0.f};  // rows 0..15
  floatx4 acc1 = {0.f, 0.f, 0.f, 0.f};  // rows 16..31

  if (!isbf) {
    // ---- x staging geometry (global_load_lds, 4 quanta per thread/chunk) --
    // LDS quantum L = j*256 + tid -> row r = j*8 + wave*2 + (lane>>5),
    // q = lane&31. LDS[r][q] holds global x[r][q ^ (r&7)] (involution).
    // Wave-uniform dest base = xs[buf] + j*4096 + wave*1024 (+lane*16 by HW).
    const int swrow = wave * 2 + (lane >> 5);        // r mod 8 contribution
    const int swz   = swrow & 7;
    const char* xbase = (const char*)xv;
    const char* gx0 = xbase + (size_t)(r0 + 0 * 8 + swrow) * (D_DIM * 4) +
                      (((lane & 31) ^ swz) << 4);
    const char* gx1 = xbase + (size_t)(r0 + 1 * 8 + swrow) * (D_DIM * 4) +
                      (((lane & 31) ^ swz) << 4);
    const char* gx2 = xbase + (size_t)(r0 + 2 * 8 + swrow) * (D_DIM * 4) +
                      (((lane & 31) ^ swz) << 4);
    const char* gx3 = xbase + (size_t)(r0 + 3 * 8 + swrow) * (D_DIM * 4) +
                      (((lane & 31) ^ swz) << 4);
    const int xdof = wave << 10;   // uniform dest offset within a j-plane

#define STAGEX(BUF, CH)                                                    \
    {                                                                      \
      char* d = xs[BUF];                                                   \
      gload16(gx0 + (size_t)(CH) * 512, d + 0 * 4096 + xdof);              \
      gload16(gx1 + (size_t)(CH) * 512, d + 1 * 4096 + xdof);              \
      gload16(gx2 + (size_t)(CH) * 512, d + 2 * 4096 + xdof);              \
      gload16(gx3 + (size_t)(CH) * 512, d + 3 * 4096 + xdof);              \
    }

    // ---- B staging: wave w stages its own 8 KB (4 steps x 2 planes x 1KB)
    // src (prep_w layout): ws + (ch*4+st)*8192 + w*2048 + p*1024 + lane*16
    // dst: bs[buf] + w*8192 + (st*2+p)*1024 (+lane*16 by HW)
    const char* wsrc = (const char*)wsv + (size_t)wave * 2048 + lane * 16;
    const int   bdof = wave << 13;

#define STAGEB(BUF, CH)                                                    \
    {                                                                      \
      char* d = bs[BUF] + bdof;                                            \
      const char* g = wsrc + (size_t)(CH) * (4 * 8192);                    \
      _Pragma("unroll")                                                    \
      for (int st = 0; st < NSTEP; ++st) {                                 \
        gload16(g + st * 8192,        d + st * 2048);                      \
        gload16(g + st * 8192 + 1024, d + st * 2048 + 1024);               \
      }                                                                    \
    }

    // A read: rows lm / lm+16 ((lm+16)&7 == lm&7), quanta 2j, 2j+1, j=K*4+t4
    const int ra0 = lm << 9;             // row lm base (512 B per row)
    const int ra1 = (lm + 16) << 9;
    const int axr = lm & 7;
    const char* bbase = bs[0];           // re-derived per chunk below

    // prologue: chunk 0 staged
    STAGEB(0, 0)
    STAGEX(0, 0)
    __syncthreads();   // hw vmcnt(0): all DMA landed

    for (int i = 0; i < NCH; ++i) {
      // 1) issue next-chunk DMA first (drained at this chunk's barrier)
      if (i + 1 < NCH) {
        STAGEB((i + 1) & 1, i + 1)
        STAGEX((i + 1) & 1, i + 1)
      }
      // 2) compute chunk i from LDS only
      const char* sx = xs[i & 1];
      const char* sb = bs[i & 1] + bdof + lane * 16;

#define STEP(K)                                                            \
    {                                                                      \
      const int q2 = ((K) * 4 + t4) * 2;                                   \
      floatx4 p0 = *(const floatx4*)(sx + ra0 + ((q2 ^ axr) << 4));        \
      floatx4 p1 = *(const floatx4*)(sx + ra0 + (((q2 + 1) ^ axr) << 4));  \
      floatx4 p2 = *(const floatx4*)(sx + ra1 + ((q2 ^ axr) << 4));        \
      floatx4 p3 = *(const floatx4*)(sx + ra1 + (((q2 + 1) ^ axr) << 4));  \
      float8 f0 = {p0[0], p0[1], p0[2], p0[3], p1[0], p1[1], p1[2], p1[3]};\
      float8 f1 = {p2[0], p2[1], p2[2], p2[3], p3[0], p3[1], p3[2], p3[3]};\
      short8 ah0, al0, ah1, al1;                                           \
      cvt_split(f0, ah0, al0);                                             \
      cvt_split(f1, ah1, al1);                                             \
      short8 bh = *(const short8*)(sb + (K) * 2048);                       \
      short8 bl = *(const short8*)(sb + (K) * 2048 + 1024);                \
      acc0 = __builtin_amdgcn_mfma_f32_16x16x32_bf16(ah0, bh, acc0, 0, 0, 0); \
      acc0 = __builtin_amdgcn_mfma_f32_16x16x32_bf16(ah0, bl, acc0, 0, 0, 0); \
      acc0 = __builtin_amdgcn_mfma_f32_16x16x32_bf16(al0, bh, acc0, 0, 0, 0); \
      acc1 = __builtin_amdgcn_mfma_f32_16x16x32_bf16(ah1, bh, acc1, 0, 0, 0); \
      acc1 = __builtin_amdgcn_mfma_f32_16x16x32_bf16(ah1, bl, acc1, 0, 0, 0); \
      acc1 = __builtin_amdgcn_mfma_f32_16x16x32_bf16(al1, bh, acc1, 0, 0, 0); \
    }

      STEP(0) STEP(1) STEP(2) STEP(3)

      // 3) barrier: drains next-chunk x and B DMA
      __syncthreads();
    }
#undef STEP
#undef STAGEB
#undef STAGEX
    (void)bbase;
  } else {
    // bf16 fallback (unexercised; register-direct, no d_ws dependency)
    const short* xp0 = (const short*)xv + (size_t)(r0 + lm) * D_DIM + t4 * 8;
    const short* xp1 = xp0 + (size_t)16 * D_DIM;
    const short* wp  = (const short*)wv + (size_t)(wave * 16 + lm) * D_DIM + t4 * 8;
    for (int k = 0; k < D_DIM; k += 32) {
      short8 a0 = *(const short8*)(xp0 + k);
      short8 a1 = *(const short8*)(xp1 + k);
      short8 b0 = *(const short8*)(wp + k);
      acc0 = __builtin_amdgcn_mfma_f32_16x16x32_bf16(a0, b0, acc0, 0, 0, 0);
      acc1 = __builtin_amdgcn_mfma_f32_16x16x32_bf16(a1, b0, acc1, 0, 0, 0);
    }
  }

  // C/D layout (m89-verified): col = lane&15 (expert), row = (lane>>4)*4 + reg
  {
    const int col   = wave * 16 + lm;
    const int rbase = t4 << 2;
#pragma unroll
    for (int r = 0; r < 4; ++r) {
      lg[rbase + r][col]      = acc0[r];
      lg[16 + rbase + r][col] = acc1[r];
    }
  }
  __syncthreads();

  if (tid < BR) {
    const int row = tid;
    float m1 = -3.4e38f, m2 = -3.4e38f;
    int   i1 = 0, i2 = 0;
    for (int e = 0; e < E_DIM; ++e) {
      float be = isbf ? __bfloat162float(((const __hip_bfloat16*)bv)[e])
                      : ((const float*)bv)[e];
      float l = lg[row][e] + be;
      if (l > m1)      { m2 = m1; i2 = i1; m1 = l; i1 = e; }
      else if (l > m2) { m2 = l;  i2 = e; }
    }
    float s = 0.f;
    for (int e = 0; e < E_DIM; ++e) {
      float be = isbf ? __bfloat162float(((const __hip_bfloat16*)bv)[e])
                      : ((const float*)bv)[e];
      s += expf(lg[row][e] + be - m1);
    }
    const int gr = r0 + row;
    // outputs concatenated flat: [N*2 indices][N*2 weights], all as float32
    out[2 * gr]                  = (float)i1;
    out[2 * gr + 1]              = (float)i2;
    out[2 * N_ROWS + 2 * gr]     = 1.0f / s;                 // exp(m1-m1)/s
    out[2 * N_ROWS + 2 * gr + 1] = expf(m2 - m1) / s;
  }
}

extern "C" void kernel_launch(void* const* d_in, const int* in_sizes, int n_in,
                              void* d_out, int out_size, void* d_ws, size_t ws_size,
                              hipStream_t stream) {
  (void)in_sizes; (void)n_in; (void)out_size; (void)ws_size;
  // prep_w writes 1 MB of fragment-ordered split-bf16 W into d_ws;
  // same-stream ordering guarantees completion before router_kernel.
  prep_w<<<dim3(64), dim3(512), 0, stream>>>(d_in[0], d_in[1], d_ws);
  router_kernel<<<dim3(N_ROWS / BR), dim3(256), 0, stream>>>(
      d_in[0], d_in[1], d_in[2], d_ws, (float*)d_out);
}